// Round 5
// baseline (2111.916 us; speedup 1.0000x reference)
//
#include <hip/hip_runtime.h>
#include <math.h>

typedef __bf16 bf16;
typedef __attribute__((ext_vector_type(8))) __bf16 bf16x8;
typedef __attribute__((ext_vector_type(4))) float f32x4;

#define NBLK 128      // edge-partition blocks for binning
#define NB_MAX 1600   // max buckets (N/64); N=100000 -> 1563

// ---------------- embedding: x0 = concat(emb_deg[deg], emb_lab[lab]) as bf16 ----------------
__global__ __launch_bounds__(256) void embed_kernel(
    const int* __restrict__ deg, const int* __restrict__ lab,
    const float* __restrict__ ed, const float* __restrict__ el,
    bf16* __restrict__ x0, int n) {
  int idx = blockIdx.x * 256 + threadIdx.x;
  if (idx >= n * 16) return;
  int node = idx >> 4, q = idx & 15;
  const float* srcp = (q < 8) ? (ed + (size_t)deg[node] * 64 + q * 8)
                              : (el + (size_t)lab[node] * 64 + (q - 8) * 8);
  float4 a = ((const float4*)srcp)[0];
  float4 b = ((const float4*)srcp)[1];
  union { bf16 h[8]; uint4 u; } out;
  out.h[0] = (bf16)a.x; out.h[1] = (bf16)a.y; out.h[2] = (bf16)a.z; out.h[3] = (bf16)a.w;
  out.h[4] = (bf16)b.x; out.h[5] = (bf16)b.y; out.h[6] = (bf16)b.z; out.h[7] = (bf16)b.w;
  *(uint4*)(x0 + (size_t)idx * 8) = out.u;
}

// ---------------- edge binning (bucket = dst>>6), no global return-atomics ----------------
// cnt layout: cnt[blk*nb + b]  (each block writes its row contiguously)
__global__ __launch_bounds__(256) void bin_hist_kernel(const int* __restrict__ dst,
                                                       int* __restrict__ cnt,
                                                       int E, int ch, int nb) {
  __shared__ int lcnt[NB_MAX];
  int tid = threadIdx.x, blk = blockIdx.x;
  for (int t = tid; t < nb; t += 256) lcnt[t] = 0;
  __syncthreads();
  int base = blk * ch, eend = min(E, base + ch);
  for (int e = base + tid; e < eend; e += 256) atomicAdd(&lcnt[dst[e] >> 6], 1);
  __syncthreads();
  for (int t = tid; t < nb; t += 256) cnt[blk * nb + t] = lcnt[t];
}

// bucket_tot[b] = sum over blk of cnt[blk][b]
__global__ __launch_bounds__(256) void bin_tot_kernel(const int* __restrict__ cnt,
                                                      int* __restrict__ tot, int nb) {
  int b = blockIdx.x * 256 + threadIdx.x;
  if (b >= nb) return;
  int s = 0;
  for (int blk = 0; blk < NBLK; ++blk) s += cnt[blk * nb + b];
  tot[b] = s;
}

// exclusive scan of bucket totals -> bucketptr[0..nb]
__global__ __launch_bounds__(256) void scan_buckets_kernel(const int* __restrict__ tot,
                                                           int* __restrict__ bucketptr, int nb) {
  __shared__ int lds[256];
  int tid = threadIdx.x;
  const int CH = 7;  // 256*7 = 1792 >= NB_MAX
  int vals[CH];
  int s = 0;
#pragma unroll
  for (int k = 0; k < CH; ++k) {
    int i = tid * CH + k;
    vals[k] = (i < nb) ? tot[i] : 0;
    s += vals[k];
  }
  lds[tid] = s;
  __syncthreads();
  for (int off = 1; off < 256; off <<= 1) {
    int v = (tid >= off) ? lds[tid - off] : 0;
    __syncthreads();
    lds[tid] += v;
    __syncthreads();
  }
  int run = lds[tid] - s;
  if (tid == 0) bucketptr[0] = 0;
#pragma unroll
  for (int k = 0; k < CH; ++k) {
    int i = tid * CH + k;
    run += vals[k];
    if (i < nb) bucketptr[i + 1] = run;
  }
}

// woff[blk*nb + b] = bucketptr[b] + sum_{blk'<blk} cnt[blk'][b]
__global__ __launch_bounds__(256) void bin_off_kernel(const int* __restrict__ cnt,
                                                      const int* __restrict__ bucketptr,
                                                      int* __restrict__ woff, int nb) {
  int b = blockIdx.x * 256 + threadIdx.x;
  if (b >= nb) return;
  int run = bucketptr[b];
  for (int blk = 0; blk < NBLK; ++blk) {
    woff[blk * nb + b] = run;
    run += cnt[blk * nb + b];
  }
}

// place packed edges: word = (dst&63)<<17 | src.  Positions exclusive per (blk,bucket).
__global__ __launch_bounds__(256) void bin_scatter_kernel(const int* __restrict__ src,
                                                          const int* __restrict__ dst,
                                                          const int* __restrict__ woff,
                                                          int* __restrict__ packed,
                                                          int E, int ch, int nb) {
  __shared__ int cur[NB_MAX];
  int tid = threadIdx.x, blk = blockIdx.x;
  for (int t = tid; t < nb; t += 256) cur[t] = woff[blk * nb + t];
  __syncthreads();
  int base = blk * ch, eend = min(E, base + ch);
  for (int e = base + tid; e < eend; e += 256) {
    int d = dst[e], s = src[e];
    int pos = atomicAdd(&cur[d >> 6], 1);
    packed[pos] = ((d & 63) << 17) | s;
  }
}

// ---------------- MFMA GEMM 0: y = x0(bf16) @ W0^T, bf16 out ----------------
__global__ __launch_bounds__(256) void mfma_gemm0(
    const bf16* __restrict__ x, const float* __restrict__ W,
    bf16* __restrict__ y, int n) {
  __shared__ bf16 As[64][136];
  __shared__ bf16 Bs[64][136];
  int tid = threadIdx.x;
  int nbase = blockIdx.x * 64;
  {
    int r = tid >> 2, c = tid & 3;
    int node = nbase + r;
    uint4 v[4] = {};
    if (node < n) {
      const uint4* p = (const uint4*)(x + (size_t)node * 128 + c * 32);
#pragma unroll
      for (int j = 0; j < 4; ++j) v[j] = p[j];
    }
#pragma unroll
    for (int j = 0; j < 4; ++j) *(uint4*)&As[r][c * 32 + j * 8] = v[j];
    const float4* wp = (const float4*)(W + r * 128 + c * 32);
#pragma unroll
    for (int j = 0; j < 4; ++j) {
      float4 f0 = wp[j * 2], f1 = wp[j * 2 + 1];
      union { bf16 h[8]; uint4 u; } t;
      t.h[0] = (bf16)f0.x; t.h[1] = (bf16)f0.y; t.h[2] = (bf16)f0.z; t.h[3] = (bf16)f0.w;
      t.h[4] = (bf16)f1.x; t.h[5] = (bf16)f1.y; t.h[6] = (bf16)f1.z; t.h[7] = (bf16)f1.w;
      *(uint4*)&Bs[r][c * 32 + j * 8] = t.u;
    }
  }
  __syncthreads();
  int l = tid & 63, w = tid >> 6, m = l & 15, quad = l >> 4;
  f32x4 acc[4] = {{0.f, 0.f, 0.f, 0.f}, {0.f, 0.f, 0.f, 0.f},
                  {0.f, 0.f, 0.f, 0.f}, {0.f, 0.f, 0.f, 0.f}};
#pragma unroll
  for (int k0 = 0; k0 < 128; k0 += 32) {
    bf16x8 a = *(const bf16x8*)&As[w * 16 + m][k0 + quad * 8];
#pragma unroll
    for (int t = 0; t < 4; ++t) {
      bf16x8 b = *(const bf16x8*)&Bs[t * 16 + m][k0 + quad * 8];
      acc[t] = __builtin_amdgcn_mfma_f32_16x16x32_bf16(a, b, acc[t], 0, 0, 0);
    }
  }
#pragma unroll
  for (int t = 0; t < 4; ++t)
#pragma unroll
    for (int r4 = 0; r4 < 4; ++r4) {
      int node = nbase + w * 16 + quad * 4 + r4;
      if (node < n) y[(size_t)node * 64 + t * 16 + m] = (bf16)acc[t][r4];
    }
}

// ------- MFMA GEMM (layers 1,2): z = leaky(bn(hin)) [bf16 out]; y = z @ W^T [bf16 out] -------
__global__ __launch_bounds__(256) void mfma_gemm_bn(
    const float* __restrict__ hin, const float* __restrict__ st,
    const float* __restrict__ W, bf16* __restrict__ z,
    bf16* __restrict__ y, int n) {
  __shared__ bf16 As[64][72];
  __shared__ bf16 Bs[64][72];
  int tid = threadIdx.x;
  int nbase = blockIdx.x * 64;
  {
    int r = tid >> 2, c = tid & 3;
    int node = nbase + r;
    union { bf16 h[16]; uint4 u[2]; } t;
    if (node < n) {
      const float4* p = (const float4*)(hin + (size_t)node * 64 + c * 16);
#pragma unroll
      for (int j = 0; j < 4; ++j) {
        float4 f = p[j];
        int d = c * 16 + j * 4;
        float v0 = f.x * st[128 + d] + st[192 + d];
        float v1 = f.y * st[129 + d] + st[193 + d];
        float v2 = f.z * st[130 + d] + st[194 + d];
        float v3 = f.w * st[131 + d] + st[195 + d];
        v0 = (v0 >= 0.f) ? v0 : 0.01f * v0;
        v1 = (v1 >= 0.f) ? v1 : 0.01f * v1;
        v2 = (v2 >= 0.f) ? v2 : 0.01f * v2;
        v3 = (v3 >= 0.f) ? v3 : 0.01f * v3;
        t.h[j * 4 + 0] = (bf16)v0; t.h[j * 4 + 1] = (bf16)v1;
        t.h[j * 4 + 2] = (bf16)v2; t.h[j * 4 + 3] = (bf16)v3;
      }
      *(uint4*)(z + (size_t)node * 64 + c * 16) = t.u[0];
      *(uint4*)(z + (size_t)node * 64 + c * 16 + 8) = t.u[1];
    } else {
      t.u[0] = uint4{0, 0, 0, 0}; t.u[1] = uint4{0, 0, 0, 0};
    }
    *(uint4*)&As[r][c * 16] = t.u[0];
    *(uint4*)&As[r][c * 16 + 8] = t.u[1];
    const float4* wp = (const float4*)(W + r * 64 + c * 16);
#pragma unroll
    for (int j = 0; j < 2; ++j) {
      float4 f0 = wp[j * 2], f1 = wp[j * 2 + 1];
      union { bf16 h[8]; uint4 u; } tw;
      tw.h[0] = (bf16)f0.x; tw.h[1] = (bf16)f0.y; tw.h[2] = (bf16)f0.z; tw.h[3] = (bf16)f0.w;
      tw.h[4] = (bf16)f1.x; tw.h[5] = (bf16)f1.y; tw.h[6] = (bf16)f1.z; tw.h[7] = (bf16)f1.w;
      *(uint4*)&Bs[r][c * 16 + j * 8] = tw.u;
    }
  }
  __syncthreads();
  int l = tid & 63, w = tid >> 6, m = l & 15, quad = l >> 4;
  f32x4 acc[4] = {{0.f, 0.f, 0.f, 0.f}, {0.f, 0.f, 0.f, 0.f},
                  {0.f, 0.f, 0.f, 0.f}, {0.f, 0.f, 0.f, 0.f}};
#pragma unroll
  for (int k0 = 0; k0 < 64; k0 += 32) {
    bf16x8 a = *(const bf16x8*)&As[w * 16 + m][k0 + quad * 8];
#pragma unroll
    for (int t = 0; t < 4; ++t) {
      bf16x8 b = *(const bf16x8*)&Bs[t * 16 + m][k0 + quad * 8];
      acc[t] = __builtin_amdgcn_mfma_f32_16x16x32_bf16(a, b, acc[t], 0, 0, 0);
    }
  }
#pragma unroll
  for (int t = 0; t < 4; ++t)
#pragma unroll
    for (int r4 = 0; r4 < 4; ++r4) {
      int node = nbase + w * 16 + quad * 4 + r4;
      if (node < n) y[(size_t)node * 64 + t * 16 + m] = (bf16)acc[t][r4];
    }
}

// ------- gather via LDS accumulators: block = bucket of 64 dst nodes -------
// acc layout [dim][node(+pad 65)]: wave ds_add bank = (lane+d)%32 -> 2-way (free)
__global__ __launch_bounds__(256) void gather_lds_kernel(
    const bf16* __restrict__ y, const int* __restrict__ packed,
    const int* __restrict__ bucketptr, const float* __restrict__ bias,
    float* __restrict__ h, float* __restrict__ stats, int n) {
  __shared__ float accf[64 * 65];
  __shared__ float s_sum[64], s_sq[64];
  int tid = threadIdx.x;
  int lane = tid & 63, wv = tid >> 6;
  for (int t = tid; t < 64 * 65; t += 256) accf[t] = 0.f;
  if (tid < 64) { s_sum[tid] = 0.f; s_sq[tid] = 0.f; }
  __syncthreads();

  int b = blockIdx.x;
  int beg = bucketptr[b], end = bucketptr[b + 1];
  int cntE = end - beg;
  int len = (cntE + 3) >> 2;
  int myb = beg + wv * len;
  int mye = min(end, myb + len);
  float* arow = accf + lane * 65;
  const bf16* yl = y + lane;
  int i = myb;
  for (; i + 8 <= mye; i += 8) {
    int w0 = packed[i], w1 = packed[i + 1], w2 = packed[i + 2], w3 = packed[i + 3];
    int w4 = packed[i + 4], w5 = packed[i + 5], w6 = packed[i + 6], w7 = packed[i + 7];
    float v0 = (float)yl[(size_t)(w0 & 0x1FFFF) * 64];
    float v1 = (float)yl[(size_t)(w1 & 0x1FFFF) * 64];
    float v2 = (float)yl[(size_t)(w2 & 0x1FFFF) * 64];
    float v3 = (float)yl[(size_t)(w3 & 0x1FFFF) * 64];
    float v4 = (float)yl[(size_t)(w4 & 0x1FFFF) * 64];
    float v5 = (float)yl[(size_t)(w5 & 0x1FFFF) * 64];
    float v6 = (float)yl[(size_t)(w6 & 0x1FFFF) * 64];
    float v7 = (float)yl[(size_t)(w7 & 0x1FFFF) * 64];
    atomicAdd(arow + (w0 >> 17), v0);
    atomicAdd(arow + (w1 >> 17), v1);
    atomicAdd(arow + (w2 >> 17), v2);
    atomicAdd(arow + (w3 >> 17), v3);
    atomicAdd(arow + (w4 >> 17), v4);
    atomicAdd(arow + (w5 >> 17), v5);
    atomicAdd(arow + (w6 >> 17), v6);
    atomicAdd(arow + (w7 >> 17), v7);
  }
  for (; i < mye; ++i) {
    int w0 = packed[i];
    float v0 = (float)yl[(size_t)(w0 & 0x1FFFF) * 64];
    atomicAdd(arow + (w0 >> 17), v0);
  }
  __syncthreads();

  // epilogue: h = y[node] + agg + bias; BN stats
  int dim = tid & 63;  // fixed per thread across iters
  float bv = bias[dim];
  float psum = 0.f, psq = 0.f;
#pragma unroll
  for (int it = 0; it < 16; ++it) {
    int flat = it * 256 + tid;
    int node = flat >> 6;
    int gnode = b * 64 + node;
    if (gnode < n) {
      float val = (float)y[(size_t)gnode * 64 + dim] + accf[dim * 65 + node] + bv;
      h[(size_t)gnode * 64 + dim] = val;
      psum += val;
      psq += val * val;
    }
  }
  atomicAdd(&s_sum[dim], psum);
  atomicAdd(&s_sq[dim], psq);
  __syncthreads();
  if (tid < 64) {
    atomicAdd(&stats[tid], s_sum[tid]);
    atomicAdd(&stats[64 + tid], s_sq[tid]);
  }
}

// ---------------- final MLP over concat [x0|z1|z2|bnleaky(h2)] (320 -> 64), MFMA ----------------
__global__ __launch_bounds__(256) void mfma_final(
    const bf16* __restrict__ x0, const bf16* __restrict__ z1,
    const bf16* __restrict__ z2, const float* __restrict__ h2,
    const float* __restrict__ st2, const float* __restrict__ fw1,
    const float* __restrict__ fb1, bf16* __restrict__ hf,
    float* __restrict__ stats, int n) {
  __shared__ bf16 As[64][136];
  __shared__ bf16 Bs[64][136];
  __shared__ float s_sum[64], s_sq[64];
  int tid = threadIdx.x;
  if (tid < 64) { s_sum[tid] = 0.f; s_sq[tid] = 0.f; }
  int nbase = blockIdx.x * 64;
  int l = tid & 63, w = tid >> 6, m = l & 15, quad = l >> 4;
  int r = tid >> 2, c = tid & 3;
  int node_r = nbase + r;
  f32x4 acc[4] = {{0.f, 0.f, 0.f, 0.f}, {0.f, 0.f, 0.f, 0.f},
                  {0.f, 0.f, 0.f, 0.f}, {0.f, 0.f, 0.f, 0.f}};

#pragma unroll
  for (int seg = 0; seg < 4; ++seg) {
    __syncthreads();
    if (seg == 0) {
      uint4 v[4] = {};
      if (node_r < n) {
        const uint4* p = (const uint4*)(x0 + (size_t)node_r * 128 + c * 32);
#pragma unroll
        for (int j = 0; j < 4; ++j) v[j] = p[j];
      }
#pragma unroll
      for (int j = 0; j < 4; ++j) *(uint4*)&As[r][c * 32 + j * 8] = v[j];
      const float4* wp = (const float4*)(fw1 + r * 320 + c * 32);
#pragma unroll
      for (int j = 0; j < 4; ++j) {
        float4 f0 = wp[j * 2], f1 = wp[j * 2 + 1];
        union { bf16 h[8]; uint4 u; } t;
        t.h[0] = (bf16)f0.x; t.h[1] = (bf16)f0.y; t.h[2] = (bf16)f0.z; t.h[3] = (bf16)f0.w;
        t.h[4] = (bf16)f1.x; t.h[5] = (bf16)f1.y; t.h[6] = (bf16)f1.z; t.h[7] = (bf16)f1.w;
        *(uint4*)&Bs[r][c * 32 + j * 8] = t.u;
      }
    } else if (seg < 3) {
      const bf16* zz = (seg == 1) ? z1 : z2;
      uint4 v[2] = {};
      if (node_r < n) {
        const uint4* p = (const uint4*)(zz + (size_t)node_r * 64 + c * 16);
        v[0] = p[0]; v[1] = p[1];
      }
      *(uint4*)&As[r][c * 16] = v[0];
      *(uint4*)&As[r][c * 16 + 8] = v[1];
      const float4* wp = (const float4*)(fw1 + r * 320 + (seg == 1 ? 128 : 192) + c * 16);
#pragma unroll
      for (int j = 0; j < 2; ++j) {
        float4 f0 = wp[j * 2], f1 = wp[j * 2 + 1];
        union { bf16 h[8]; uint4 u; } t;
        t.h[0] = (bf16)f0.x; t.h[1] = (bf16)f0.y; t.h[2] = (bf16)f0.z; t.h[3] = (bf16)f0.w;
        t.h[4] = (bf16)f1.x; t.h[5] = (bf16)f1.y; t.h[6] = (bf16)f1.z; t.h[7] = (bf16)f1.w;
        *(uint4*)&Bs[r][c * 16 + j * 8] = t.u;
      }
    } else {
      union { bf16 h[16]; uint4 u[2]; } t;
      if (node_r < n) {
        const float4* p = (const float4*)(h2 + (size_t)node_r * 64 + c * 16);
#pragma unroll
        for (int j = 0; j < 4; ++j) {
          float4 f = p[j];
          int d = c * 16 + j * 4;
          float v0 = f.x * st2[128 + d] + st2[192 + d];
          float v1 = f.y * st2[129 + d] + st2[193 + d];
          float v2 = f.z * st2[130 + d] + st2[194 + d];
          float v3 = f.w * st2[131 + d] + st2[195 + d];
          v0 = (v0 >= 0.f) ? v0 : 0.01f * v0;
          v1 = (v1 >= 0.f) ? v1 : 0.01f * v1;
          v2 = (v2 >= 0.f) ? v2 : 0.01f * v2;
          v3 = (v3 >= 0.f) ? v3 : 0.01f * v3;
          t.h[j * 4 + 0] = (bf16)v0; t.h[j * 4 + 1] = (bf16)v1;
          t.h[j * 4 + 2] = (bf16)v2; t.h[j * 4 + 3] = (bf16)v3;
        }
      } else {
        t.u[0] = uint4{0, 0, 0, 0}; t.u[1] = uint4{0, 0, 0, 0};
      }
      *(uint4*)&As[r][c * 16] = t.u[0];
      *(uint4*)&As[r][c * 16 + 8] = t.u[1];
      const float4* wp = (const float4*)(fw1 + r * 320 + 256 + c * 16);
#pragma unroll
      for (int j = 0; j < 2; ++j) {
        float4 f0 = wp[j * 2], f1 = wp[j * 2 + 1];
        union { bf16 h[8]; uint4 u; } tw;
        tw.h[0] = (bf16)f0.x; tw.h[1] = (bf16)f0.y; tw.h[2] = (bf16)f0.z; tw.h[3] = (bf16)f0.w;
        tw.h[4] = (bf16)f1.x; tw.h[5] = (bf16)f1.y; tw.h[6] = (bf16)f1.z; tw.h[7] = (bf16)f1.w;
        *(uint4*)&Bs[r][c * 16 + j * 8] = tw.u;
      }
    }
    __syncthreads();
    int kmax = (seg == 0) ? 128 : 64;
    for (int k0 = 0; k0 < kmax; k0 += 32) {
      bf16x8 a = *(const bf16x8*)&As[w * 16 + m][k0 + quad * 8];
#pragma unroll
      for (int t = 0; t < 4; ++t) {
        bf16x8 b = *(const bf16x8*)&Bs[t * 16 + m][k0 + quad * 8];
        acc[t] = __builtin_amdgcn_mfma_f32_16x16x32_bf16(a, b, acc[t], 0, 0, 0);
      }
    }
  }

#pragma unroll
  for (int t = 0; t < 4; ++t) {
    int o = t * 16 + m;
    float bv = fb1[o];
    float s = 0.f, q = 0.f;
#pragma unroll
    for (int r4 = 0; r4 < 4; ++r4) {
      int node = nbase + w * 16 + quad * 4 + r4;
      if (node < n) {
        float v = acc[t][r4] + bv;
        hf[(size_t)node * 64 + o] = (bf16)v;
        s += v;
        q += v * v;
      }
    }
    atomicAdd(&s_sum[o], s);
    atomicAdd(&s_sq[o], q);
  }
  __syncthreads();
  if (tid < 64) {
    atomicAdd(&stats[tid], s_sum[tid]);
    atomicAdd(&stats[64 + tid], s_sq[tid]);
  }
}

// ---------------- BN finalize: scale/shift ----------------
__global__ void bn_finalize_kernel(float* __restrict__ st, const float* __restrict__ g,
                                   const float* __restrict__ be, float inv_n) {
  int o = threadIdx.x;
  if (o < 64) {
    float mean = st[o] * inv_n;
    float var = st[64 + o] * inv_n - mean * mean;
    float sc = g[o] * rsqrtf(var + 1e-5f);
    st[128 + o] = sc;
    st[192 + o] = be[o] - mean * sc;
  }
}

// ---------------- head: sigmoid(leaky(bn(hf)) @ fw2^T + fb2) ----------------
__global__ __launch_bounds__(256) void final_out_kernel(const bf16* __restrict__ hf,
                                                        const float* __restrict__ st,
                                                        const float* __restrict__ fw2,
                                                        const float* __restrict__ fb2,
                                                        float* __restrict__ out, int n) {
  int lane = threadIdx.x & 63;
  int node = blockIdx.x * 4 + (threadIdx.x >> 6);
  if (node >= n) return;
  float v = (float)hf[(size_t)node * 64 + lane] * st[128 + lane] + st[192 + lane];
  v = (v >= 0.f) ? v : 0.01f * v;
  v *= fw2[lane];
#pragma unroll
  for (int off = 32; off > 0; off >>= 1) v += __shfl_xor(v, off);
  if (lane == 0) out[node] = 1.f / (1.f + expf(-(v + fb2[0])));
}

extern "C" void kernel_launch(void* const* d_in, const int* in_sizes, int n_in,
                              void* d_out, int out_size, void* d_ws, size_t ws_size,
                              hipStream_t stream) {
  const int* node_deg = (const int*)d_in[0];
  const int* node_lab = (const int*)d_in[1];
  const int* ei = (const int*)d_in[2];
  const float* emb_deg = (const float*)d_in[3];
  const float* emb_lab = (const float*)d_in[4];
  const float* w0 = (const float*)d_in[5];
  const float* b0 = (const float*)d_in[6];
  const float* g0 = (const float*)d_in[7];
  const float* be0 = (const float*)d_in[8];
  const float* w1 = (const float*)d_in[9];
  const float* b1 = (const float*)d_in[10];
  const float* g1 = (const float*)d_in[11];
  const float* be1 = (const float*)d_in[12];
  const float* w2 = (const float*)d_in[13];
  const float* b2 = (const float*)d_in[14];
  const float* g2 = (const float*)d_in[15];
  const float* be2 = (const float*)d_in[16];
  const float* fw1 = (const float*)d_in[17];
  const float* fb1 = (const float*)d_in[18];
  const float* fg = (const float*)d_in[19];
  const float* fbe = (const float*)d_in[20];
  const float* fw2 = (const float*)d_in[21];
  const float* fb2 = (const float*)d_in[22];

  const int N = in_sizes[0];
  const int E = in_sizes[2] / 2;
  const int* src = ei;
  const int* dst = ei + E;
  const int NB = (N + 63) >> 6;            // buckets of 64 dst nodes
  const int CH = (E + NBLK - 1) / NBLK;    // edges per binning block

  char* ws = (char*)d_ws;
  size_t off = 0;
  auto alloc = [&](size_t bytes) {
    void* p = ws + off;
    off += (bytes + 255) & ~(size_t)255;
    return p;
  };
  bf16* x0 = (bf16*)alloc((size_t)N * 128 * 2);
  bf16* z1 = (bf16*)alloc((size_t)N * 64 * 2);
  bf16* z2 = (bf16*)alloc((size_t)N * 64 * 2);
  float* h = (float*)alloc((size_t)N * 64 * 4);
  bf16* y = (bf16*)alloc((size_t)N * 64 * 2);  // reused as hf at the end
  int* packed = (int*)alloc((size_t)E * 4);
  int* cnt = (int*)alloc((size_t)NBLK * NB * 4);
  int* woff = (int*)alloc((size_t)NBLK * NB * 4);
  int* btot = (int*)alloc((size_t)NB * 4);
  int* bucketptr = (int*)alloc((size_t)(NB + 1) * 4);
  float* stats = (float*)alloc(4 * 256 * 4);

  hipMemsetAsync(stats, 0, 4 * 256 * 4, stream);

  embed_kernel<<<(N * 16 + 255) / 256, 256, 0, stream>>>(node_deg, node_lab, emb_deg,
                                                         emb_lab, x0, N);
  // edge binning (replaces hist/scan/cursor/scatter)
  bin_hist_kernel<<<NBLK, 256, 0, stream>>>(dst, cnt, E, CH, NB);
  bin_tot_kernel<<<(NB + 255) / 256, 256, 0, stream>>>(cnt, btot, NB);
  scan_buckets_kernel<<<1, 256, 0, stream>>>(btot, bucketptr, NB);
  bin_off_kernel<<<(NB + 255) / 256, 256, 0, stream>>>(cnt, bucketptr, woff, NB);
  bin_scatter_kernel<<<NBLK, 256, 0, stream>>>(src, dst, woff, packed, E, CH, NB);

  int ngrid = (N + 63) / 64;

  // layer 0
  mfma_gemm0<<<ngrid, 256, 0, stream>>>(x0, w0, y, N);
  gather_lds_kernel<<<NB, 256, 0, stream>>>(y, packed, bucketptr, b0, h, stats, N);
  bn_finalize_kernel<<<1, 64, 0, stream>>>(stats, g0, be0, 1.0f / N);
  // layer 1
  mfma_gemm_bn<<<ngrid, 256, 0, stream>>>(h, stats, w1, z1, y, N);
  gather_lds_kernel<<<NB, 256, 0, stream>>>(y, packed, bucketptr, b1, h, stats + 256, N);
  bn_finalize_kernel<<<1, 64, 0, stream>>>(stats + 256, g1, be1, 1.0f / N);
  // layer 2
  mfma_gemm_bn<<<ngrid, 256, 0, stream>>>(h, stats + 256, w2, z2, y, N);
  gather_lds_kernel<<<NB, 256, 0, stream>>>(y, packed, bucketptr, b2, h, stats + 512, N);
  bn_finalize_kernel<<<1, 64, 0, stream>>>(stats + 512, g2, be2, 1.0f / N);
  // final MLP 320 -> 64 (z3 inline from h2); hf reuses y buffer (bf16)
  mfma_final<<<ngrid, 256, 0, stream>>>(x0, z1, z2, h, stats + 512, fw1, fb1, y,
                                        stats + 768, N);
  bn_finalize_kernel<<<1, 64, 0, stream>>>(stats + 768, fg, fbe, 1.0f / N);
  final_out_kernel<<<(N + 3) / 4, 256, 0, stream>>>(y, stats + 768, fw2, fb2,
                                                    (float*)d_out, N);
}

// Round 6
// 622.922 us; speedup vs baseline: 3.3903x; 3.3903x over previous
//
#include <hip/hip_runtime.h>
#include <math.h>

typedef __bf16 bf16;
typedef __attribute__((ext_vector_type(8))) __bf16 bf16x8;
typedef __attribute__((ext_vector_type(4))) float f32x4;

#define NBLK 128      // edge-partition blocks for binning
#define NB_MAX 1600   // max buckets (N/64); N=100000 -> 1563

// ---------------- embedding: x0 = concat(emb_deg[deg], emb_lab[lab]) as bf16 ----------------
__global__ __launch_bounds__(256) void embed_kernel(
    const int* __restrict__ deg, const int* __restrict__ lab,
    const float* __restrict__ ed, const float* __restrict__ el,
    bf16* __restrict__ x0, int n) {
  int idx = blockIdx.x * 256 + threadIdx.x;
  if (idx >= n * 16) return;
  int node = idx >> 4, q = idx & 15;
  const float* srcp = (q < 8) ? (ed + (size_t)deg[node] * 64 + q * 8)
                              : (el + (size_t)lab[node] * 64 + (q - 8) * 8);
  float4 a = ((const float4*)srcp)[0];
  float4 b = ((const float4*)srcp)[1];
  union { bf16 h[8]; uint4 u; } out;
  out.h[0] = (bf16)a.x; out.h[1] = (bf16)a.y; out.h[2] = (bf16)a.z; out.h[3] = (bf16)a.w;
  out.h[4] = (bf16)b.x; out.h[5] = (bf16)b.y; out.h[6] = (bf16)b.z; out.h[7] = (bf16)b.w;
  *(uint4*)(x0 + (size_t)idx * 8) = out.u;
}

// ---------------- edge binning (bucket = dst>>6), no contended global return-atomics ----------------
__global__ __launch_bounds__(256) void bin_hist_kernel(const int* __restrict__ dst,
                                                       int* __restrict__ cnt,
                                                       int E, int ch, int nb) {
  __shared__ int lcnt[NB_MAX];
  int tid = threadIdx.x, blk = blockIdx.x;
  for (int t = tid; t < nb; t += 256) lcnt[t] = 0;
  __syncthreads();
  int base = blk * ch, eend = min(E, base + ch);
  for (int e = base + tid; e < eend; e += 256) atomicAdd(&lcnt[dst[e] >> 6], 1);
  __syncthreads();
  for (int t = tid; t < nb; t += 256) cnt[blk * nb + t] = lcnt[t];
}

__global__ __launch_bounds__(256) void bin_tot_kernel(const int* __restrict__ cnt,
                                                      int* __restrict__ tot, int nb) {
  int b = blockIdx.x * 256 + threadIdx.x;
  if (b >= nb) return;
  int s = 0;
  for (int blk = 0; blk < NBLK; ++blk) s += cnt[blk * nb + b];
  tot[b] = s;
}

__global__ __launch_bounds__(256) void scan_buckets_kernel(const int* __restrict__ tot,
                                                           int* __restrict__ bucketptr, int nb) {
  __shared__ int lds[256];
  int tid = threadIdx.x;
  const int CH = 7;  // 256*7 = 1792 >= NB_MAX
  int vals[CH];
  int s = 0;
#pragma unroll
  for (int k = 0; k < CH; ++k) {
    int i = tid * CH + k;
    vals[k] = (i < nb) ? tot[i] : 0;
    s += vals[k];
  }
  lds[tid] = s;
  __syncthreads();
  for (int off = 1; off < 256; off <<= 1) {
    int v = (tid >= off) ? lds[tid - off] : 0;
    __syncthreads();
    lds[tid] += v;
    __syncthreads();
  }
  int run = lds[tid] - s;
  if (tid == 0) bucketptr[0] = 0;
#pragma unroll
  for (int k = 0; k < CH; ++k) {
    int i = tid * CH + k;
    run += vals[k];
    if (i < nb) bucketptr[i + 1] = run;
  }
}

__global__ __launch_bounds__(256) void bin_off_kernel(const int* __restrict__ cnt,
                                                      const int* __restrict__ bucketptr,
                                                      int* __restrict__ woff, int nb) {
  int b = blockIdx.x * 256 + threadIdx.x;
  if (b >= nb) return;
  int run = bucketptr[b];
  for (int blk = 0; blk < NBLK; ++blk) {
    woff[blk * nb + b] = run;
    run += cnt[blk * nb + b];
  }
}

// place packed edges: word = (dst&63)<<17 | src.  Positions exclusive per (blk,bucket).
__global__ __launch_bounds__(256) void bin_scatter_kernel(const int* __restrict__ src,
                                                          const int* __restrict__ dst,
                                                          const int* __restrict__ woff,
                                                          int* __restrict__ packed,
                                                          int E, int ch, int nb) {
  __shared__ int cur[NB_MAX];
  int tid = threadIdx.x, blk = blockIdx.x;
  for (int t = tid; t < nb; t += 256) cur[t] = woff[blk * nb + t];
  __syncthreads();
  int base = blk * ch, eend = min(E, base + ch);
  for (int e = base + tid; e < eend; e += 256) {
    int d = dst[e], s = src[e];
    int pos = atomicAdd(&cur[d >> 6], 1);
    packed[pos] = ((d & 63) << 17) | s;
  }
}

// regroup bucket-mixed packed edges into node-grouped colidx + rowptr (writes stay in 4KB window)
__global__ __launch_bounds__(256) void csr_finalize_kernel(
    const int* __restrict__ packed, const int* __restrict__ bucketptr,
    int* __restrict__ rowptr, int* __restrict__ colidx, int n, int E) {
  __shared__ int hist[64], offs[64];
  int tid = threadIdx.x, b = blockIdx.x;
  if (tid < 64) hist[tid] = 0;
  __syncthreads();
  int beg = bucketptr[b], end = bucketptr[b + 1];
  for (int e = beg + tid; e < end; e += 256) atomicAdd(&hist[packed[e] >> 17], 1);
  __syncthreads();
  if (tid == 0) {
    int run = 0;
    for (int j = 0; j < 64; ++j) { offs[j] = run; run += hist[j]; }
  }
  __syncthreads();
  if (tid < 64) {
    int idx = b * 64 + tid;
    if (idx < n) rowptr[idx] = beg + offs[tid];
    hist[tid] = offs[tid];  // reuse as cursor
  }
  if (b == 0 && tid == 64) rowptr[n] = E;
  __syncthreads();
  for (int e = beg + tid; e < end; e += 256) {
    int w = packed[e];
    int pos = atomicAdd(&hist[w >> 17], 1);
    colidx[beg + pos] = w & 0x1FFFF;
  }
}

// ---------------- MFMA GEMM 0: y = x0(bf16) @ W0^T, bf16 out ----------------
__global__ __launch_bounds__(256) void mfma_gemm0(
    const bf16* __restrict__ x, const float* __restrict__ W,
    bf16* __restrict__ y, int n) {
  __shared__ bf16 As[64][136];
  __shared__ bf16 Bs[64][136];
  int tid = threadIdx.x;
  int nbase = blockIdx.x * 64;
  {
    int r = tid >> 2, c = tid & 3;
    int node = nbase + r;
    uint4 v[4] = {};
    if (node < n) {
      const uint4* p = (const uint4*)(x + (size_t)node * 128 + c * 32);
#pragma unroll
      for (int j = 0; j < 4; ++j) v[j] = p[j];
    }
#pragma unroll
    for (int j = 0; j < 4; ++j) *(uint4*)&As[r][c * 32 + j * 8] = v[j];
    const float4* wp = (const float4*)(W + r * 128 + c * 32);
#pragma unroll
    for (int j = 0; j < 4; ++j) {
      float4 f0 = wp[j * 2], f1 = wp[j * 2 + 1];
      union { bf16 h[8]; uint4 u; } t;
      t.h[0] = (bf16)f0.x; t.h[1] = (bf16)f0.y; t.h[2] = (bf16)f0.z; t.h[3] = (bf16)f0.w;
      t.h[4] = (bf16)f1.x; t.h[5] = (bf16)f1.y; t.h[6] = (bf16)f1.z; t.h[7] = (bf16)f1.w;
      *(uint4*)&Bs[r][c * 32 + j * 8] = t.u;
    }
  }
  __syncthreads();
  int l = tid & 63, w = tid >> 6, m = l & 15, quad = l >> 4;
  f32x4 acc[4] = {{0.f, 0.f, 0.f, 0.f}, {0.f, 0.f, 0.f, 0.f},
                  {0.f, 0.f, 0.f, 0.f}, {0.f, 0.f, 0.f, 0.f}};
#pragma unroll
  for (int k0 = 0; k0 < 128; k0 += 32) {
    bf16x8 a = *(const bf16x8*)&As[w * 16 + m][k0 + quad * 8];
#pragma unroll
    for (int t = 0; t < 4; ++t) {
      bf16x8 b = *(const bf16x8*)&Bs[t * 16 + m][k0 + quad * 8];
      acc[t] = __builtin_amdgcn_mfma_f32_16x16x32_bf16(a, b, acc[t], 0, 0, 0);
    }
  }
#pragma unroll
  for (int t = 0; t < 4; ++t)
#pragma unroll
    for (int r4 = 0; r4 < 4; ++r4) {
      int node = nbase + w * 16 + quad * 4 + r4;
      if (node < n) y[(size_t)node * 64 + t * 16 + m] = (bf16)acc[t][r4];
    }
}

// ------- MFMA GEMM (layers 1,2): z = leaky(bn(hin bf16)); y = z @ W^T [bf16 out] -------
__global__ __launch_bounds__(256) void mfma_gemm_bn(
    const bf16* __restrict__ hin, const float* __restrict__ st,
    const float* __restrict__ W, bf16* __restrict__ z,
    bf16* __restrict__ y, int n) {
  __shared__ bf16 As[64][72];
  __shared__ bf16 Bs[64][72];
  int tid = threadIdx.x;
  int nbase = blockIdx.x * 64;
  {
    int r = tid >> 2, c = tid & 3;
    int node = nbase + r;
    union { bf16 h[16]; uint4 u[2]; } t;
    if (node < n) {
      const uint4* p = (const uint4*)(hin + (size_t)node * 64 + c * 16);
      union { uint4 u; bf16 h[8]; } a0, a1;
      a0.u = p[0]; a1.u = p[1];
#pragma unroll
      for (int j = 0; j < 8; ++j) {
        int d = c * 16 + j;
        float v = (float)a0.h[j] * st[128 + d] + st[192 + d];
        v = (v >= 0.f) ? v : 0.01f * v;
        t.h[j] = (bf16)v;
      }
#pragma unroll
      for (int j = 0; j < 8; ++j) {
        int d = c * 16 + 8 + j;
        float v = (float)a1.h[j] * st[128 + d] + st[192 + d];
        v = (v >= 0.f) ? v : 0.01f * v;
        t.h[8 + j] = (bf16)v;
      }
      *(uint4*)(z + (size_t)node * 64 + c * 16) = t.u[0];
      *(uint4*)(z + (size_t)node * 64 + c * 16 + 8) = t.u[1];
    } else {
      t.u[0] = uint4{0, 0, 0, 0}; t.u[1] = uint4{0, 0, 0, 0};
    }
    *(uint4*)&As[r][c * 16] = t.u[0];
    *(uint4*)&As[r][c * 16 + 8] = t.u[1];
    const float4* wp = (const float4*)(W + r * 64 + c * 16);
#pragma unroll
    for (int j = 0; j < 2; ++j) {
      float4 f0 = wp[j * 2], f1 = wp[j * 2 + 1];
      union { bf16 h[8]; uint4 u; } tw;
      tw.h[0] = (bf16)f0.x; tw.h[1] = (bf16)f0.y; tw.h[2] = (bf16)f0.z; tw.h[3] = (bf16)f0.w;
      tw.h[4] = (bf16)f1.x; tw.h[5] = (bf16)f1.y; tw.h[6] = (bf16)f1.z; tw.h[7] = (bf16)f1.w;
      *(uint4*)&Bs[r][c * 16 + j * 8] = tw.u;
    }
  }
  __syncthreads();
  int l = tid & 63, w = tid >> 6, m = l & 15, quad = l >> 4;
  f32x4 acc[4] = {{0.f, 0.f, 0.f, 0.f}, {0.f, 0.f, 0.f, 0.f},
                  {0.f, 0.f, 0.f, 0.f}, {0.f, 0.f, 0.f, 0.f}};
#pragma unroll
  for (int k0 = 0; k0 < 64; k0 += 32) {
    bf16x8 a = *(const bf16x8*)&As[w * 16 + m][k0 + quad * 8];
#pragma unroll
    for (int t = 0; t < 4; ++t) {
      bf16x8 b = *(const bf16x8*)&Bs[t * 16 + m][k0 + quad * 8];
      acc[t] = __builtin_amdgcn_mfma_f32_16x16x32_bf16(a, b, acc[t], 0, 0, 0);
    }
  }
#pragma unroll
  for (int t = 0; t < 4; ++t)
#pragma unroll
    for (int r4 = 0; r4 < 4; ++r4) {
      int node = nbase + w * 16 + quad * 4 + r4;
      if (node < n) y[(size_t)node * 64 + t * 16 + m] = (bf16)acc[t][r4];
    }
}

// ------- register gather, 2 nodes/wave interleaved (16 row-loads in flight) -------
__global__ __launch_bounds__(256) void gather_kernel(
    const bf16* __restrict__ y, const int* __restrict__ rowptr,
    const int* __restrict__ colidx, const float* __restrict__ bias,
    bf16* __restrict__ h, float* __restrict__ stats, int n) {
  __shared__ float s_sum[64], s_sq[64];
  int tid = threadIdx.x;
  if (tid < 64) { s_sum[tid] = 0.f; s_sq[tid] = 0.f; }
  __syncthreads();
  int lane = tid & 63, wv = tid >> 6;
  float bv = bias[lane];
  float psum = 0.f, psq = 0.f;
  int stride = gridDim.x * 8;
  const bf16* yl = y + lane;
  for (int nodeA = blockIdx.x * 8 + wv * 2; nodeA < n; nodeA += stride) {
    int nodeB = nodeA + 1;
    bool hasB = nodeB < n;
    float acc0 = (float)yl[(size_t)nodeA * 64] + bv;
    float acc1 = hasB ? (float)yl[(size_t)nodeB * 64] + bv : 0.f;
    int e0 = rowptr[nodeA], f0 = rowptr[nodeA + 1];
    int e1 = hasB ? rowptr[nodeB] : 0;
    int f1 = hasB ? rowptr[nodeB + 1] : 0;
    while (e0 + 8 <= f0 && e1 + 8 <= f1) {
      int a0 = colidx[e0], a1 = colidx[e0 + 1], a2 = colidx[e0 + 2], a3 = colidx[e0 + 3];
      int a4 = colidx[e0 + 4], a5 = colidx[e0 + 5], a6 = colidx[e0 + 6], a7 = colidx[e0 + 7];
      int b0 = colidx[e1], b1 = colidx[e1 + 1], b2 = colidx[e1 + 2], b3 = colidx[e1 + 3];
      int b4 = colidx[e1 + 4], b5 = colidx[e1 + 5], b6 = colidx[e1 + 6], b7 = colidx[e1 + 7];
      float va0 = (float)yl[(size_t)a0 * 64], va1 = (float)yl[(size_t)a1 * 64];
      float va2 = (float)yl[(size_t)a2 * 64], va3 = (float)yl[(size_t)a3 * 64];
      float va4 = (float)yl[(size_t)a4 * 64], va5 = (float)yl[(size_t)a5 * 64];
      float va6 = (float)yl[(size_t)a6 * 64], va7 = (float)yl[(size_t)a7 * 64];
      float vb0 = (float)yl[(size_t)b0 * 64], vb1 = (float)yl[(size_t)b1 * 64];
      float vb2 = (float)yl[(size_t)b2 * 64], vb3 = (float)yl[(size_t)b3 * 64];
      float vb4 = (float)yl[(size_t)b4 * 64], vb5 = (float)yl[(size_t)b5 * 64];
      float vb6 = (float)yl[(size_t)b6 * 64], vb7 = (float)yl[(size_t)b7 * 64];
      acc0 += ((va0 + va1) + (va2 + va3)) + ((va4 + va5) + (va6 + va7));
      acc1 += ((vb0 + vb1) + (vb2 + vb3)) + ((vb4 + vb5) + (vb6 + vb7));
      e0 += 8; e1 += 8;
    }
    for (; e0 + 4 <= f0; e0 += 4) {
      int a0 = colidx[e0], a1 = colidx[e0 + 1], a2 = colidx[e0 + 2], a3 = colidx[e0 + 3];
      float v0 = (float)yl[(size_t)a0 * 64], v1 = (float)yl[(size_t)a1 * 64];
      float v2 = (float)yl[(size_t)a2 * 64], v3 = (float)yl[(size_t)a3 * 64];
      acc0 += (v0 + v1) + (v2 + v3);
    }
    for (; e0 < f0; ++e0) acc0 += (float)yl[(size_t)colidx[e0] * 64];
    for (; e1 + 4 <= f1; e1 += 4) {
      int b0 = colidx[e1], b1 = colidx[e1 + 1], b2 = colidx[e1 + 2], b3 = colidx[e1 + 3];
      float v0 = (float)yl[(size_t)b0 * 64], v1 = (float)yl[(size_t)b1 * 64];
      float v2 = (float)yl[(size_t)b2 * 64], v3 = (float)yl[(size_t)b3 * 64];
      acc1 += (v0 + v1) + (v2 + v3);
    }
    for (; e1 < f1; ++e1) acc1 += (float)yl[(size_t)colidx[e1] * 64];
    h[(size_t)nodeA * 64 + lane] = (bf16)acc0;
    psum += acc0; psq += acc0 * acc0;
    if (hasB) {
      h[(size_t)nodeB * 64 + lane] = (bf16)acc1;
      psum += acc1; psq += acc1 * acc1;
    }
  }
  atomicAdd(&s_sum[lane], psum);
  atomicAdd(&s_sq[lane], psq);
  __syncthreads();
  if (tid < 64) {
    atomicAdd(&stats[tid], s_sum[tid]);
    atomicAdd(&stats[64 + tid], s_sq[tid]);
  }
}

// ---------------- final MLP over concat [x0|z1|z2|bnleaky(h2)] (320 -> 64), MFMA ----------------
__global__ __launch_bounds__(256) void mfma_final(
    const bf16* __restrict__ x0, const bf16* __restrict__ z1,
    const bf16* __restrict__ z2, const bf16* __restrict__ h2,
    const float* __restrict__ st2, const float* __restrict__ fw1,
    const float* __restrict__ fb1, bf16* __restrict__ hf,
    float* __restrict__ stats, int n) {
  __shared__ bf16 As[64][136];
  __shared__ bf16 Bs[64][136];
  __shared__ float s_sum[64], s_sq[64];
  int tid = threadIdx.x;
  if (tid < 64) { s_sum[tid] = 0.f; s_sq[tid] = 0.f; }
  int nbase = blockIdx.x * 64;
  int l = tid & 63, w = tid >> 6, m = l & 15, quad = l >> 4;
  int r = tid >> 2, c = tid & 3;
  int node_r = nbase + r;
  f32x4 acc[4] = {{0.f, 0.f, 0.f, 0.f}, {0.f, 0.f, 0.f, 0.f},
                  {0.f, 0.f, 0.f, 0.f}, {0.f, 0.f, 0.f, 0.f}};

#pragma unroll
  for (int seg = 0; seg < 4; ++seg) {
    __syncthreads();
    if (seg == 0) {
      uint4 v[4] = {};
      if (node_r < n) {
        const uint4* p = (const uint4*)(x0 + (size_t)node_r * 128 + c * 32);
#pragma unroll
        for (int j = 0; j < 4; ++j) v[j] = p[j];
      }
#pragma unroll
      for (int j = 0; j < 4; ++j) *(uint4*)&As[r][c * 32 + j * 8] = v[j];
      const float4* wp = (const float4*)(fw1 + r * 320 + c * 32);
#pragma unroll
      for (int j = 0; j < 4; ++j) {
        float4 f0 = wp[j * 2], f1 = wp[j * 2 + 1];
        union { bf16 h[8]; uint4 u; } t;
        t.h[0] = (bf16)f0.x; t.h[1] = (bf16)f0.y; t.h[2] = (bf16)f0.z; t.h[3] = (bf16)f0.w;
        t.h[4] = (bf16)f1.x; t.h[5] = (bf16)f1.y; t.h[6] = (bf16)f1.z; t.h[7] = (bf16)f1.w;
        *(uint4*)&Bs[r][c * 32 + j * 8] = t.u;
      }
    } else if (seg < 3) {
      const bf16* zz = (seg == 1) ? z1 : z2;
      uint4 v[2] = {};
      if (node_r < n) {
        const uint4* p = (const uint4*)(zz + (size_t)node_r * 64 + c * 16);
        v[0] = p[0]; v[1] = p[1];
      }
      *(uint4*)&As[r][c * 16] = v[0];
      *(uint4*)&As[r][c * 16 + 8] = v[1];
      const float4* wp = (const float4*)(fw1 + r * 320 + (seg == 1 ? 128 : 192) + c * 16);
#pragma unroll
      for (int j = 0; j < 2; ++j) {
        float4 f0 = wp[j * 2], f1 = wp[j * 2 + 1];
        union { bf16 h[8]; uint4 u; } t;
        t.h[0] = (bf16)f0.x; t.h[1] = (bf16)f0.y; t.h[2] = (bf16)f0.z; t.h[3] = (bf16)f0.w;
        t.h[4] = (bf16)f1.x; t.h[5] = (bf16)f1.y; t.h[6] = (bf16)f1.z; t.h[7] = (bf16)f1.w;
        *(uint4*)&Bs[r][c * 16 + j * 8] = t.u;
      }
    } else {
      union { bf16 h[16]; uint4 u[2]; } t;
      if (node_r < n) {
        const uint4* p = (const uint4*)(h2 + (size_t)node_r * 64 + c * 16);
        union { uint4 u; bf16 h[8]; } a0, a1;
        a0.u = p[0]; a1.u = p[1];
#pragma unroll
        for (int j = 0; j < 8; ++j) {
          int d = c * 16 + j;
          float v = (float)a0.h[j] * st2[128 + d] + st2[192 + d];
          v = (v >= 0.f) ? v : 0.01f * v;
          t.h[j] = (bf16)v;
        }
#pragma unroll
        for (int j = 0; j < 8; ++j) {
          int d = c * 16 + 8 + j;
          float v = (float)a1.h[j] * st2[128 + d] + st2[192 + d];
          v = (v >= 0.f) ? v : 0.01f * v;
          t.h[8 + j] = (bf16)v;
        }
      } else {
        t.u[0] = uint4{0, 0, 0, 0}; t.u[1] = uint4{0, 0, 0, 0};
      }
      *(uint4*)&As[r][c * 16] = t.u[0];
      *(uint4*)&As[r][c * 16 + 8] = t.u[1];
      const float4* wp = (const float4*)(fw1 + r * 320 + 256 + c * 16);
#pragma unroll
      for (int j = 0; j < 2; ++j) {
        float4 f0 = wp[j * 2], f1 = wp[j * 2 + 1];
        union { bf16 h[8]; uint4 u; } tw;
        tw.h[0] = (bf16)f0.x; tw.h[1] = (bf16)f0.y; tw.h[2] = (bf16)f0.z; tw.h[3] = (bf16)f0.w;
        tw.h[4] = (bf16)f1.x; tw.h[5] = (bf16)f1.y; tw.h[6] = (bf16)f1.z; tw.h[7] = (bf16)f1.w;
        *(uint4*)&Bs[r][c * 16 + j * 8] = tw.u;
      }
    }
    __syncthreads();
    int kmax = (seg == 0) ? 128 : 64;
    for (int k0 = 0; k0 < kmax; k0 += 32) {
      bf16x8 a = *(const bf16x8*)&As[w * 16 + m][k0 + quad * 8];
#pragma unroll
      for (int t = 0; t < 4; ++t) {
        bf16x8 b = *(const bf16x8*)&Bs[t * 16 + m][k0 + quad * 8];
        acc[t] = __builtin_amdgcn_mfma_f32_16x16x32_bf16(a, b, acc[t], 0, 0, 0);
      }
    }
  }

#pragma unroll
  for (int t = 0; t < 4; ++t) {
    int o = t * 16 + m;
    float bv = fb1[o];
    float s = 0.f, q = 0.f;
#pragma unroll
    for (int r4 = 0; r4 < 4; ++r4) {
      int node = nbase + w * 16 + quad * 4 + r4;
      if (node < n) {
        float v = acc[t][r4] + bv;
        hf[(size_t)node * 64 + o] = (bf16)v;
        s += v;
        q += v * v;
      }
    }
    atomicAdd(&s_sum[o], s);
    atomicAdd(&s_sq[o], q);
  }
  __syncthreads();
  if (tid < 64) {
    atomicAdd(&stats[tid], s_sum[tid]);
    atomicAdd(&stats[64 + tid], s_sq[tid]);
  }
}

// ---------------- BN finalize: scale/shift ----------------
__global__ void bn_finalize_kernel(float* __restrict__ st, const float* __restrict__ g,
                                   const float* __restrict__ be, float inv_n) {
  int o = threadIdx.x;
  if (o < 64) {
    float mean = st[o] * inv_n;
    float var = st[64 + o] * inv_n - mean * mean;
    float sc = g[o] * rsqrtf(var + 1e-5f);
    st[128 + o] = sc;
    st[192 + o] = be[o] - mean * sc;
  }
}

// ---------------- head: sigmoid(leaky(bn(hf)) @ fw2^T + fb2) ----------------
__global__ __launch_bounds__(256) void final_out_kernel(const bf16* __restrict__ hf,
                                                        const float* __restrict__ st,
                                                        const float* __restrict__ fw2,
                                                        const float* __restrict__ fb2,
                                                        float* __restrict__ out, int n) {
  int lane = threadIdx.x & 63;
  int node = blockIdx.x * 4 + (threadIdx.x >> 6);
  if (node >= n) return;
  float v = (float)hf[(size_t)node * 64 + lane] * st[128 + lane] + st[192 + lane];
  v = (v >= 0.f) ? v : 0.01f * v;
  v *= fw2[lane];
#pragma unroll
  for (int off = 32; off > 0; off >>= 1) v += __shfl_xor(v, off);
  if (lane == 0) out[node] = 1.f / (1.f + expf(-(v + fb2[0])));
}

extern "C" void kernel_launch(void* const* d_in, const int* in_sizes, int n_in,
                              void* d_out, int out_size, void* d_ws, size_t ws_size,
                              hipStream_t stream) {
  const int* node_deg = (const int*)d_in[0];
  const int* node_lab = (const int*)d_in[1];
  const int* ei = (const int*)d_in[2];
  const float* emb_deg = (const float*)d_in[3];
  const float* emb_lab = (const float*)d_in[4];
  const float* w0 = (const float*)d_in[5];
  const float* b0 = (const float*)d_in[6];
  const float* g0 = (const float*)d_in[7];
  const float* be0 = (const float*)d_in[8];
  const float* w1 = (const float*)d_in[9];
  const float* b1 = (const float*)d_in[10];
  const float* g1 = (const float*)d_in[11];
  const float* be1 = (const float*)d_in[12];
  const float* w2 = (const float*)d_in[13];
  const float* b2 = (const float*)d_in[14];
  const float* g2 = (const float*)d_in[15];
  const float* be2 = (const float*)d_in[16];
  const float* fw1 = (const float*)d_in[17];
  const float* fb1 = (const float*)d_in[18];
  const float* fg = (const float*)d_in[19];
  const float* fbe = (const float*)d_in[20];
  const float* fw2 = (const float*)d_in[21];
  const float* fb2 = (const float*)d_in[22];

  const int N = in_sizes[0];
  const int E = in_sizes[2] / 2;
  const int* src = ei;
  const int* dst = ei + E;
  const int NB = (N + 63) >> 6;
  const int CH = (E + NBLK - 1) / NBLK;

  char* ws = (char*)d_ws;
  size_t off = 0;
  auto alloc = [&](size_t bytes) {
    void* p = ws + off;
    off += (bytes + 255) & ~(size_t)255;
    return p;
  };
  bf16* x0 = (bf16*)alloc((size_t)N * 128 * 2);
  bf16* z1 = (bf16*)alloc((size_t)N * 64 * 2);
  bf16* z2 = (bf16*)alloc((size_t)N * 64 * 2);
  bf16* h = (bf16*)alloc((size_t)N * 64 * 2);
  bf16* y = (bf16*)alloc((size_t)N * 64 * 2);  // reused as hf at the end
  int* packed = (int*)alloc((size_t)E * 4);
  int* colidx = (int*)alloc((size_t)E * 4);
  int* rowptr = (int*)alloc((size_t)(N + 1) * 4);
  int* cnt = (int*)alloc((size_t)NBLK * NB * 4);
  int* woff = (int*)alloc((size_t)NBLK * NB * 4);
  int* btot = (int*)alloc((size_t)NB * 4);
  int* bucketptr = (int*)alloc((size_t)(NB + 1) * 4);
  float* stats = (float*)alloc(4 * 256 * 4);

  hipMemsetAsync(stats, 0, 4 * 256 * 4, stream);

  embed_kernel<<<(N * 16 + 255) / 256, 256, 0, stream>>>(node_deg, node_lab, emb_deg,
                                                         emb_lab, x0, N);
  // CSR build: contention-free binning + per-bucket regroup
  bin_hist_kernel<<<NBLK, 256, 0, stream>>>(dst, cnt, E, CH, NB);
  bin_tot_kernel<<<(NB + 255) / 256, 256, 0, stream>>>(cnt, btot, NB);
  scan_buckets_kernel<<<1, 256, 0, stream>>>(btot, bucketptr, NB);
  bin_off_kernel<<<(NB + 255) / 256, 256, 0, stream>>>(cnt, bucketptr, woff, NB);
  bin_scatter_kernel<<<NBLK, 256, 0, stream>>>(src, dst, woff, packed, E, CH, NB);
  csr_finalize_kernel<<<NB, 256, 0, stream>>>(packed, bucketptr, rowptr, colidx, N, E);

  int ngrid = (N + 63) / 64;
  int ggrid = 2048;

  // layer 0
  mfma_gemm0<<<ngrid, 256, 0, stream>>>(x0, w0, y, N);
  gather_kernel<<<ggrid, 256, 0, stream>>>(y, rowptr, colidx, b0, h, stats, N);
  bn_finalize_kernel<<<1, 64, 0, stream>>>(stats, g0, be0, 1.0f / N);
  // layer 1
  mfma_gemm_bn<<<ngrid, 256, 0, stream>>>(h, stats, w1, z1, y, N);
  gather_kernel<<<ggrid, 256, 0, stream>>>(y, rowptr, colidx, b1, h, stats + 256, N);
  bn_finalize_kernel<<<1, 64, 0, stream>>>(stats + 256, g1, be1, 1.0f / N);
  // layer 2
  mfma_gemm_bn<<<ngrid, 256, 0, stream>>>(h, stats + 256, w2, z2, y, N);
  gather_kernel<<<ggrid, 256, 0, stream>>>(y, rowptr, colidx, b2, h, stats + 512, N);
  bn_finalize_kernel<<<1, 64, 0, stream>>>(stats + 512, g2, be2, 1.0f / N);
  // final MLP 320 -> 64 (z3 inline from h2); hf reuses y buffer (bf16)
  mfma_final<<<ngrid, 256, 0, stream>>>(x0, z1, z2, h, stats + 512, fw1, fb1, y,
                                        stats + 768, N);
  bn_finalize_kernel<<<1, 64, 0, stream>>>(stats + 768, fg, fbe, 1.0f / N);
  final_out_kernel<<<(N + 3) / 4, 256, 0, stream>>>(y, stats + 768, fw2, fb2,
                                                    (float*)d_out, N);
}